// Round 1
// baseline (4549.726 us; speedup 1.0000x reference)
//
#include <hip/hip_runtime.h>
#include <hip/hip_bf16.h>

// LSTM: B=1024, T=256, INPUT=64, HIDDEN=512, NUM_CLASSES=10
// Strategy (round 1): 256 step-kernel launches; each step is a fused
// [1024 x 576] x [576 x 2048] f16-MFMA GEMM + gate activations + c/h update.
// K = 512 (h part) + 64 (x_t part, converted fp32->f16 on the fly).
// Gate columns interleaved n' = 4*jj + gate so a lane-quad holds i,f,g,o of
// one hidden unit -> combine with __shfl_xor, no LDS epilogue round-trip.

#define T_STEPS 256
#define BATCH   1024
#define HID     512
#define INSZ    64
#define KTOT    576
#define NCLS    10

typedef _Float16 f16x8 __attribute__((ext_vector_type(8)));
typedef float    f32x16 __attribute__((ext_vector_type(16)));

__device__ __forceinline__ float tanh_f(float x) {
    return 2.0f / (1.0f + __expf(-2.0f * x)) - 1.0f;
}

// ---------------- prep: pack weights (f16), bias, initial state ----------------
__global__ __launch_bounds__(256) void prep_kernel(
    const float* __restrict__ Whh, const float* __restrict__ Wih,
    const float* __restrict__ bih, const float* __restrict__ bhh,
    const float* __restrict__ h0,  const float* __restrict__ c0,
    _Float16* __restrict__ Wc, float* __restrict__ bias,
    _Float16* __restrict__ hb, float* __restrict__ cb)
{
    int idx = blockIdx.x * 256 + threadIdx.x;
    if (idx < 4 * HID * KTOT) {
        int n = idx / KTOT, k = idx - n * KTOT;
        float v = (k < HID) ? Whh[n * HID + k] : Wih[n * INSZ + (k - HID)];
        Wc[idx] = (_Float16)v;
    }
    if (idx < 4 * HID) bias[idx] = bih[idx] + bhh[idx];
    if (idx < BATCH * HID) { hb[idx] = (_Float16)h0[idx]; cb[idx] = c0[idx]; }
}

// ---------------- one LSTM time step ----------------
// grid 256: block -> (m0 = 64-row batch tile, j0 = 32 hidden units)
// block tile: 64 x 128 gate-cols, waves 2x2, wave tile 32 x 64 (2 MFMA 32x32 tiles)
__global__ __launch_bounds__(256) void lstm_step_kernel(
    const _Float16* __restrict__ Wc, const float* __restrict__ bias,
    const float* __restrict__ x, const _Float16* __restrict__ h_in,
    _Float16* __restrict__ h_out, float* __restrict__ cb, int t)
{
    __shared__ __align__(16) _Float16 As[64][72];   // +8 pad: row stride 144B
    __shared__ __align__(16) _Float16 Bs[128][72];

    const int tid  = threadIdx.x;
    const int lane = tid & 63;
    const int wid  = tid >> 6;
    const int wm   = wid & 1;      // m half (32 rows)
    const int wn   = wid >> 1;     // n' half (64 cols)
    const int m0   = (blockIdx.x >> 4) * 64;
    const int j0   = (blockIdx.x & 15) * 32;

    const int l31   = lane & 31;
    const int khalf = (lane >> 5) * 8;

    f32x16 acc0, acc1;
    #pragma unroll
    for (int i = 0; i < 16; ++i) { acc0[i] = 0.0f; acc1[i] = 0.0f; }

    for (int kc = 0; kc < 9; ++kc) {
        // ---- stage A tile 64x64 (h for kc<8, x_t for kc==8) ----
        #pragma unroll
        for (int it = 0; it < 2; ++it) {
            int flat = (it * 256 + tid) * 8;        // 0..4088
            int r = flat >> 6, cc = flat & 63;
            if (kc < 8) {
                uint4 v = *(const uint4*)(h_in + (size_t)(m0 + r) * HID + kc * 64 + cc);
                *(f16x8*)(&As[r][cc]) = __builtin_bit_cast(f16x8, v);
            } else {
                const float* xp = x + (size_t)(m0 + r) * (T_STEPS * INSZ) + t * INSZ + cc;
                float4 f0 = *(const float4*)xp;
                float4 f1 = *(const float4*)(xp + 4);
                f16x8 o;
                o[0] = (_Float16)f0.x; o[1] = (_Float16)f0.y;
                o[2] = (_Float16)f0.z; o[3] = (_Float16)f0.w;
                o[4] = (_Float16)f1.x; o[5] = (_Float16)f1.y;
                o[6] = (_Float16)f1.z; o[7] = (_Float16)f1.w;
                *(f16x8*)(&As[r][cc]) = o;
            }
        }
        // ---- stage B tile 128x64: row n' = 4*jj + gate -> W row gate*512+j0+jj ----
        #pragma unroll
        for (int it = 0; it < 4; ++it) {
            int flat = (it * 256 + tid) * 8;        // 0..8184
            int npr = flat >> 6, cc = flat & 63;
            int gate = npr & 3, jj = npr >> 2;
            int n = gate * HID + j0 + jj;
            uint4 v = *(const uint4*)(Wc + (size_t)n * KTOT + kc * 64 + cc);
            *(f16x8*)(&Bs[npr][cc]) = __builtin_bit_cast(f16x8, v);
        }
        __syncthreads();
        // ---- MFMA: 4 k-tiles of 16 ----
        #pragma unroll
        for (int kt = 0; kt < 4; ++kt) {
            f16x8 af = *(const f16x8*)(&As[wm * 32 + l31][kt * 16 + khalf]);
            f16x8 b0 = *(const f16x8*)(&Bs[wn * 64 + l31][kt * 16 + khalf]);
            f16x8 b1 = *(const f16x8*)(&Bs[wn * 64 + 32 + l31][kt * 16 + khalf]);
            acc0 = __builtin_amdgcn_mfma_f32_32x32x16_f16(af, b0, acc0, 0, 0, 0);
            acc1 = __builtin_amdgcn_mfma_f32_32x32x16_f16(af, b1, acc1, 0, 0, 0);
        }
        __syncthreads();
    }

    // ---- epilogue: C/D layout col=lane&31, row=(reg&3)+8*(reg>>2)+4*(lane>>5) ----
    // gate = n'&3 = lane&3 : quad lanes hold i,f,g,o of the same (m, j).
    const int rowhi = (lane >> 5) * 4;
    #pragma unroll
    for (int nt = 0; nt < 2; ++nt) {
        f32x16 acc = (nt == 0) ? acc0 : acc1;
        int np   = wn * 64 + nt * 32 + l31;
        int gate = np & 3;
        int j    = j0 + (np >> 2);
        float bsv = bias[gate * HID + j];
        float s   = (gate == 2) ? 2.0f : 1.0f;   // tanh for g, sigmoid otherwise
        #pragma unroll
        for (int r = 0; r < 16; ++r) {
            int row = (r & 3) + 8 * (r >> 2) + rowhi;
            int m = m0 + wm * 32 + row;
            float v = acc[r] + bsv;
            float e = __expf(-s * v);
            float a = s / (1.0f + e) - (s - 1.0f); // sigmoid or tanh, branchless
            float v1 = __shfl_xor(a, 1);
            float v2 = __shfl_xor(a, 2);
            float v3 = __shfl_xor(a, 3);
            if ((gate & 3) == 0) {               // quad leader: a=i, v1=f, v2=g, v3=o
                size_t off = (size_t)m * HID + j;
                float c_old = cb[off];
                float cn = v1 * c_old + a * v2;
                float hn = v3 * tanh_f(cn);
                cb[off] = cn;
                h_out[off] = (_Float16)hn;
            }
        }
    }
}

// ---------------- final linear: preds = hT @ W_lin^T + b_lin ----------------
__global__ __launch_bounds__(256) void final_kernel(
    const _Float16* __restrict__ h, const float* __restrict__ Wl,
    const float* __restrict__ bl, float* __restrict__ out)
{
    int i = blockIdx.x * 256 + threadIdx.x;
    if (i >= BATCH * NCLS) return;
    int b = i / NCLS, c = i - b * NCLS;
    const _Float16* hp = h + (size_t)b * HID;
    const float* wp = Wl + (size_t)c * HID;
    float sacc = bl[c];
    for (int k = 0; k < HID; ++k) sacc += (float)hp[k] * wp[k];
    out[i] = sacc;
}

extern "C" void kernel_launch(void* const* d_in, const int* in_sizes, int n_in,
                              void* d_out, int out_size, void* d_ws, size_t ws_size,
                              hipStream_t stream)
{
    const float* x    = (const float*)d_in[0];
    const float* h0   = (const float*)d_in[1];
    const float* c0   = (const float*)d_in[2];
    const float* Wih  = (const float*)d_in[3];
    const float* Whh  = (const float*)d_in[4];
    const float* bih  = (const float*)d_in[5];
    const float* bhh  = (const float*)d_in[6];
    const float* Wlin = (const float*)d_in[7];
    const float* blin = (const float*)d_in[8];
    float* out = (float*)d_out;

    // workspace layout (16B-aligned offsets), total ~6.3 MB
    char* ws = (char*)d_ws;
    _Float16* Wc   = (_Float16*)(ws);                 // 2048*576*2 = 2359296
    float*    bias = (float*)  (ws + 2359296);        // 8192
    _Float16* hb0  = (_Float16*)(ws + 2367488);       // 1048576
    _Float16* hb1  = (_Float16*)(ws + 3416064);       // 1048576
    float*    cb   = (float*)  (ws + 4464640);        // 2097152

    prep_kernel<<<4608, 256, 0, stream>>>(Whh, Wih, bih, bhh, h0, c0, Wc, bias, hb0, cb);

    for (int t = 0; t < T_STEPS; ++t) {
        const _Float16* hin = (t & 1) ? hb1 : hb0;    // t=0 reads h0 (hb0)
        _Float16*      hout = (t & 1) ? hb0 : hb1;
        lstm_step_kernel<<<256, 256, 0, stream>>>(Wc, bias, x, hin, hout, cb, t);
    }
    // t=255 (odd) wrote hb0
    final_kernel<<<40, 256, 0, stream>>>(hb0, Wlin, blin, out);
}